// Round 2
// baseline (529.492 us; speedup 1.0000x reference)
//
#include <hip/hip_runtime.h>
#include <stdint.h>

// CondConceptSampler: single-query attention per (b,g) with GroupNorm'd q,k.
// Algebra: GN(k) affine per (b,g) -> softmax(sim) depends only on
// rs * (w . x[:,n]) with w[c] = sum_s qhat[s]*g2[s]*Wk[s,c]; mean/beta drop out.
// rs needs Var(K) over (s,n):  SumK  = <colsum(Wk), rowsum(X)>   (exact, fp32)
//                              SumK2 = <M, X X^T>, M = Wk^T Wk   (bf16 MFMA Gram)
// Gram contracts over n (contiguous) -> MFMA fragments are plain ds_read_b128.
//
// B=8 G=32 BW=64 S=64 CD=256 N=4096.  x: [8,2048,4096] fp32 (268 MB).

#define EPS 1e-5f
#define NN 4096
#define CHUNK 256
#define NCHUNK 16
#define NSTR 264   // LDS tile row stride in shorts (528B = 33*16B, bank-uniform)

typedef __bf16 bf16x8 __attribute__((ext_vector_type(8)));
typedef float f32x4 __attribute__((ext_vector_type(4)));

// ---- Kernel A: q-path -> w_all[bg][c] --------------------------------------
__global__ __launch_bounds__(64) void kA(const float* __restrict__ sent,
                                         const float* __restrict__ Wq,
                                         const float* __restrict__ Wk,
                                         const float* __restrict__ g1,
                                         const float* __restrict__ b1,
                                         const float* __restrict__ g2,
                                         float* __restrict__ w_all) {
  int bg = blockIdx.x; int b = bg >> 5; int g = bg & 31;
  int t = threadIdx.x;                       // t = s index (one wave)
  const float* wqrow = Wq + (size_t)(g * 64 + t) * 256;
  const float* se = sent + b * 256;
  float q = 0.f;
  for (int c = 0; c < 256; c += 4) {
    float4 wv = *(const float4*)(wqrow + c);
    q += se[c] * wv.x + se[c + 1] * wv.y + se[c + 2] * wv.z + se[c + 3] * wv.w;
  }
  float s = q;
  for (int off = 32; off; off >>= 1) s += __shfl_xor(s, off);
  float mu = s * (1.f / 64.f);
  float d = q - mu;
  float v = d * d;
  for (int off = 32; off; off >>= 1) v += __shfl_xor(v, off);
  float rsq = rsqrtf(v * (1.f / 64.f) + EPS);
  int gs = g * 64 + t;
  float qg2 = (d * rsq * g1[gs] + b1[gs]) * g2[gs];  // coefficient on K[s,n]
  __shared__ float qs[64];
  qs[t] = qg2;
  __syncthreads();
  float wacc = 0.f;                          // w[c], c = t
  for (int s2 = 0; s2 < 64; s2++)
    wacc += qs[s2] * Wk[(size_t)(g * 64 + s2) * 64 + t];
  w_all[bg * 64 + t] = wacc;
}

// ---- Kernel M: per g: M = Wk^T Wk (fp32) and cw = colsum_s(Wk) -------------
__global__ __launch_bounds__(256) void kM(const float* __restrict__ Wk,
                                          float* __restrict__ M,
                                          float* __restrict__ cw) {
  int g = blockIdx.x; int t = threadIdx.x;
  __shared__ float wk[4096];                 // Wk[g] : [s=64][c=64]
  const float* wg = Wk + (size_t)g * 4096;
  #pragma unroll
  for (int i = 0; i < 16; i++) wk[t + 256 * i] = wg[t + 256 * i];
  __syncthreads();
  int c = t & 63, q = t >> 6;                // q wave-uniform -> broadcast reads
  float acc[16];
  #pragma unroll
  for (int i = 0; i < 16; i++) acc[i] = 0.f;
  for (int s = 0; s < 64; s++) {
    float a = wk[s * 64 + c];
    const float* r = &wk[s * 64 + q * 16];
    #pragma unroll
    for (int i = 0; i < 16; i++) acc[i] += a * r[i];
  }
  float* Mg = M + (size_t)g * 4096;
  #pragma unroll
  for (int i = 0; i < 16; i++) Mg[(q * 16 + i) * 64 + c] = acc[i];
  if (t < 64) {
    float s2 = 0.f;
    for (int s = 0; s < 64; s++) s2 += wk[s * 64 + t];
    cw[g * 64 + t] = s2;
  }
}

// ---- Kernel B: per (bg, n-chunk): y[n] = w.x (fp32), SumK partial (fp32),
// ----           SumK2 partial via bf16 Gram MFMA + <M, .> contraction -------
__global__ __launch_bounds__(256, 4) void kB(const float* __restrict__ x,
                                             const float* __restrict__ w_all,
                                             const float* __restrict__ cw,
                                             const float* __restrict__ M,
                                             float* __restrict__ y_all,
                                             float* __restrict__ sums_part) {
  int bg = blockIdx.y; int b = bg >> 5; int g = bg & 31;
  int n0 = blockIdx.x * CHUNK;
  int t = threadIdx.x;
  int lane = t & 63;
  int wv = t >> 6;

  __shared__ unsigned short xt[64 * NSTR];   // bf16 tile [c][n], 33792 B
  __shared__ float ypart[4 * 256];           // 4 KB
  __shared__ float red[8];

  // Staging: wave wv owns c = wv + 4k; lane owns n = lane*4..+3.
  const float* xb = x + ((size_t)(b * 2048 + g * 64)) * NN + n0;
  const float* wp = w_all + bg * 64;         // wave-uniform -> scalar loads
  const float* cwp = cw + g * 64;
  float y0 = 0, y1 = 0, y2 = 0, y3 = 0, zt = 0;
  #pragma unroll 4
  for (int k = 0; k < 16; k++) {
    int c = wv + 4 * k;
    float4 vx = *(const float4*)(xb + (size_t)c * NN + lane * 4);
    float wc = wp[c], cc = cwp[c];
    y0 += wc * vx.x; y1 += wc * vx.y; y2 += wc * vx.z; y3 += wc * vx.w;
    zt += cc * (vx.x + vx.y + vx.z + vx.w);
    // bf16 pack: +0x8000 round-half, truncate (0.5 ulp, fine for variance)
    unsigned a0 = __builtin_bit_cast(unsigned, vx.x) + 0x8000u;
    unsigned a1 = __builtin_bit_cast(unsigned, vx.y) + 0x8000u;
    unsigned a2 = __builtin_bit_cast(unsigned, vx.z) + 0x8000u;
    unsigned a3 = __builtin_bit_cast(unsigned, vx.w) + 0x8000u;
    uint2 pk;
    pk.x = (a0 >> 16) | (a1 & 0xffff0000u);
    pk.y = (a2 >> 16) | (a3 & 0xffff0000u);
    *(uint2*)&xt[c * NSTR + lane * 4] = pk;
  }
  {
    float4 yp; yp.x = y0; yp.y = y1; yp.z = y2; yp.w = y3;
    *(float4*)&ypart[wv * 256 + lane * 4] = yp;
  }
  __syncthreads();
  // y final (fp32): thread t -> column t
  y_all[(size_t)bg * NN + n0 + t] =
      ypart[t] + ypart[256 + t] + ypart[512 + t] + ypart[768 + t];

  // Gram MFMA: wave wv computes tile-row wv of C = X X^T (4 16x16 tiles).
  // A-frag and B-frags share the same lane formula -> 4 b128 loads/k-step.
  int rbase = (lane & 15) * NSTR;
  int koff = (lane >> 4) * 8;
  f32x4 acc[4];
  #pragma unroll
  for (int r = 0; r < 4; r++) acc[r] = (f32x4){0.f, 0.f, 0.f, 0.f};
  #pragma unroll
  for (int kk = 0; kk < 8; kk++) {
    bf16x8 frg[4];
    #pragma unroll
    for (int r = 0; r < 4; r++)
      frg[r] = *(const bf16x8*)&xt[r * 16 * NSTR + rbase + kk * 32 + koff];
    bf16x8 af = frg[wv];
    #pragma unroll
    for (int r = 0; r < 4; r++)
      acc[r] = __builtin_amdgcn_mfma_f32_16x16x32_bf16(af, frg[r], acc[r], 0, 0, 0);
  }
  // <M, Gram> : lane holds C[row=(l>>4)*4+i][col=l&15] of tile (wv, r)
  float s2acc = 0.f;
  {
    const float* Mg = M + (size_t)g * 4096;
    int row = wv * 16 + (lane >> 4) * 4, col = lane & 15;
    #pragma unroll
    for (int r = 0; r < 4; r++) {
      const float* mrow = Mg + r * 16 + col;
      #pragma unroll
      for (int i = 0; i < 4; i++) s2acc += acc[r][i] * mrow[(row + i) * 64];
    }
  }
  for (int off = 32; off; off >>= 1) {
    zt += __shfl_xor(zt, off);
    s2acc += __shfl_xor(s2acc, off);
  }
  if (lane == 0) { red[wv] = zt; red[4 + wv] = s2acc; }
  __syncthreads();
  if (t == 0) {
    float* sp = sums_part + (size_t)(blockIdx.x * 256 + bg) * 2;
    sp[0] = red[0] + red[1] + red[2] + red[3];
    sp[1] = red[4] + red[5] + red[6] + red[7];
  }
}

// ---- Kernel C: per bg: rs from summed partials, softmax over 4096 logits ---
__global__ __launch_bounds__(256) void kC(const float* __restrict__ y_all,
                                          const float* __restrict__ sums_part,
                                          float* __restrict__ attn) {
  int bg = blockIdx.x; int t = threadIdx.x;
  float s1 = 0.f, s2 = 0.f;
  for (int i = 0; i < NCHUNK; i++) {
    const float* sp = sums_part + (size_t)(i * 256 + bg) * 2;
    s1 += sp[0]; s2 += sp[1];
  }
  float mu = s1 * (1.f / 262144.f);
  float var = s2 * (1.f / 262144.f) - mu * mu;
  float rs = rsqrtf(var + EPS);
  const float* y = y_all + (size_t)bg * NN;
  float l[16];
  float m = -1e30f;
  #pragma unroll
  for (int i = 0; i < 16; i++) {
    l[i] = rs * y[t + 256 * i];
    m = fmaxf(m, l[i]);
  }
  __shared__ float red[8];
  for (int off = 32; off; off >>= 1) m = fmaxf(m, __shfl_xor(m, off));
  int wv = t >> 6, lane = t & 63;
  if (lane == 0) red[wv] = m;
  __syncthreads();
  m = fmaxf(fmaxf(red[0], red[1]), fmaxf(red[2], red[3]));
  float sum = 0.f;
  #pragma unroll
  for (int i = 0; i < 16; i++) { l[i] = __expf(l[i] - m); sum += l[i]; }
  for (int off = 32; off; off >>= 1) sum += __shfl_xor(sum, off);
  if (lane == 0) red[4 + wv] = sum;
  __syncthreads();
  float inv = 1.f / (red[4] + red[5] + red[6] + red[7]);
  float* ao = attn + (size_t)bg * NN;
  #pragma unroll
  for (int i = 0; i < 16; i++) ao[t + 256 * i] = l[i] * inv;
}

// ---- Kernel D: outp[j][bg][c] = sum_{n in chunk j} attn[n]*x[c,n] ----------
__global__ __launch_bounds__(256, 4) void kD(const float* __restrict__ x,
                                             const float* __restrict__ attn,
                                             float* __restrict__ outp) {
  // Reverse order: anti-LRU re-read of x against the 256 MiB L3.
  int bg = 255 - blockIdx.y; int b = bg >> 5; int g = bg & 31;
  int n0b = (3 - blockIdx.x) * 1024;
  int t = threadIdx.x; int lane = t & 63; int wv = t >> 6;
  const float* xb = x + ((size_t)(b * 2048 + g * 64)) * NN;
  const float* ab = attn + (size_t)bg * NN;
  float p[16];
  #pragma unroll
  for (int k = 0; k < 16; k++) p[k] = 0.f;
  for (int s = 0; s < 4; s++) {
    int n0 = n0b + s * 256;
    float4 a = *(const float4*)(ab + n0 + lane * 4);
    #pragma unroll 4
    for (int k = 0; k < 16; k++) {
      int c = wv + 4 * k;
      float4 vx = *(const float4*)(xb + (size_t)c * NN + n0 + lane * 4);
      p[k] += a.x * vx.x + a.y * vx.y + a.z * vx.z + a.w * vx.w;
    }
  }
  #pragma unroll
  for (int k = 0; k < 16; k++) {
    float r = p[k];
    for (int off = 32; off; off >>= 1) r += __shfl_xor(r, off);
    if (lane == 0) outp[(size_t)blockIdx.x * 16384 + bg * 64 + wv + 4 * k] = r;
  }
}

// ---- Kernel E: out[bg][s] = sum_c (sum_j outp[j][bg][c]) * Wv[g][s][c] -----
__global__ __launch_bounds__(64) void kE(const float* __restrict__ outp,
                                         const float* __restrict__ Wv,
                                         float* __restrict__ out) {
  int bg = blockIdx.x; int g = bg & 31;
  int t = threadIdx.x;
  __shared__ float oc[64];
  __shared__ float wvs[64 * 65];
  oc[t] = outp[bg * 64 + t] + outp[16384 + bg * 64 + t] +
          outp[32768 + bg * 64 + t] + outp[49152 + bg * 64 + t];
  const float* wg = Wv + (size_t)g * 4096;
  for (int i = 0; i < 64; i++) wvs[i * 65 + t] = wg[i * 64 + t];
  __syncthreads();
  float acc = 0.f;
  for (int c = 0; c < 64; c++) acc += wvs[t * 65 + c] * oc[c];
  out[bg * 64 + t] = acc;
}

extern "C" void kernel_launch(void* const* d_in, const int* in_sizes, int n_in,
                              void* d_out, int out_size, void* d_ws, size_t ws_size,
                              hipStream_t stream) {
  const float* x    = (const float*)d_in[0];
  const float* sent = (const float*)d_in[1];
  const float* Wq   = (const float*)d_in[2];
  const float* Wk   = (const float*)d_in[3];
  const float* Wv   = (const float*)d_in[4];
  const float* g1   = (const float*)d_in[5];
  const float* b1   = (const float*)d_in[6];
  const float* g2   = (const float*)d_in[7];
  // d_in[8] = beta2: drops out of softmax (shift-invariance) — unused.
  float* out = (float*)d_out;

  char* ws = (char*)d_ws;
  float* w_all = (float*)(ws);                 // 256*64*4       = 64 KB
  float* cw    = (float*)(ws + 65536);         // 32*64*4        = 8 KB
  float* M     = (float*)(ws + 73728);         // 32*64*64*4     = 512 KB
  float* sumsp = (float*)(ws + 598016);        // 16*256*2*4     = 32 KB
  float* outp  = (float*)(ws + 630784);        // 4*256*64*4     = 256 KB
  float* y_all = (float*)(ws + 892928);        // 256*4096*4     = 4 MB
  float* attn  = (float*)(ws + 5087232);       // 4 MB

  kA<<<256, 64, 0, stream>>>(sent, Wq, Wk, g1, b1, g2, w_all);
  kM<<<32, 256, 0, stream>>>(Wk, M, cw);
  kB<<<dim3(NCHUNK, 256), 256, 0, stream>>>(x, w_all, cw, M, y_all, sumsp);
  kC<<<256, 256, 0, stream>>>(y_all, sumsp, attn);
  kD<<<dim3(4, 256), 256, 0, stream>>>(x, attn, outp);
  kE<<<256, 64, 0, stream>>>(outp, Wv, out);
}

// Round 3
// 433.226 us; speedup vs baseline: 1.2222x; 1.2222x over previous
//
#include <hip/hip_runtime.h>
#include <stdint.h>

// CondConceptSampler: single-query attention per (b,g) with GroupNorm'd q,k.
// Algebra: GN(k) affine per (b,g) -> softmax(sim) depends only on
// rs * (w . x[:,n]) with w[c] = sum_s qhat[s]*g2[s]*Wk[s,c]; mean/beta drop out.
// rs needs Var(K) over (s,n):  SumK  = <colsum(Wk), rowsum(X)>   (exact, fp32)
//                              SumK2 = <M, X X^T>, M = Wk^T Wk   (bf16 MFMA Gram)
// R3: latency-bound fix — batched loads (16 dwordx4 in flight), coalesced
// pre-permuted M (no scatter), no dynamic register indexing, kD 16 blocks/CU.
//
// B=8 G=32 BW=64 S=64 CD=256 N=4096.  x: [8,2048,4096] fp32 (268 MB).

#define EPS 1e-5f
#define NN 4096
#define NCHUNK 16
#define NSTR 264   // LDS tile row stride in shorts (528B = 33*16B)

typedef __bf16 bf16x8 __attribute__((ext_vector_type(8)));
typedef float f32x4 __attribute__((ext_vector_type(4)));

// ---- Kernel A: q-path -> w_all[bg][c] --------------------------------------
__global__ __launch_bounds__(64) void kA(const float* __restrict__ sent,
                                         const float* __restrict__ Wq,
                                         const float* __restrict__ Wk,
                                         const float* __restrict__ g1,
                                         const float* __restrict__ b1,
                                         const float* __restrict__ g2,
                                         float* __restrict__ w_all) {
  int bg = blockIdx.x; int b = bg >> 5; int g = bg & 31;
  int t = threadIdx.x;                       // t = s index (one wave)
  const float* wqrow = Wq + (size_t)(g * 64 + t) * 256;
  const float* se = sent + b * 256;
  float q = 0.f;
  for (int c = 0; c < 256; c += 4) {
    float4 wv = *(const float4*)(wqrow + c);
    q += se[c] * wv.x + se[c + 1] * wv.y + se[c + 2] * wv.z + se[c + 3] * wv.w;
  }
  float s = q;
  for (int off = 32; off; off >>= 1) s += __shfl_xor(s, off);
  float mu = s * (1.f / 64.f);
  float d = q - mu;
  float v = d * d;
  for (int off = 32; off; off >>= 1) v += __shfl_xor(v, off);
  float rsq = rsqrtf(v * (1.f / 64.f) + EPS);
  int gs = g * 64 + t;
  float qg2 = (d * rsq * g1[gs] + b1[gs]) * g2[gs];  // coefficient on K[s,n]
  __shared__ float qs[64];
  qs[t] = qg2;
  __syncthreads();
  float wacc = 0.f;                          // w[c], c = t
  for (int s2 = 0; s2 < 64; s2++)
    wacc += qs[s2] * Wk[(size_t)(g * 64 + s2) * 64 + t];
  w_all[bg * 64 + t] = wacc;
}

// ---- Kernel M: per g: M = Wk^T Wk, permuted to Mp[g][r][t] (float4);
// ----           cw = colsum_s(Wk) -------------------------------------------
__global__ __launch_bounds__(256) void kM(const float* __restrict__ Wk,
                                          float4* __restrict__ Mp,
                                          float* __restrict__ cw) {
  int g = blockIdx.x; int t = threadIdx.x;
  __shared__ float wk[4096];                 // Wk[g] : [s=64][c=64]
  __shared__ float Ml[64 * 65];              // M padded
  const float* wg = Wk + (size_t)g * 4096;
  #pragma unroll
  for (int i = 0; i < 16; i++) wk[t + 256 * i] = wg[t + 256 * i];
  __syncthreads();
  int c = t & 63, q = t >> 6;                // q wave-uniform -> broadcast reads
  float acc[16];
  #pragma unroll
  for (int i = 0; i < 16; i++) acc[i] = 0.f;
  for (int s = 0; s < 64; s++) {
    float a = wk[s * 64 + c];
    const float* r = &wk[s * 64 + q * 16];
    #pragma unroll
    for (int i = 0; i < 16; i++) acc[i] += a * r[i];
  }
  #pragma unroll
  for (int i = 0; i < 16; i++) Ml[(q * 16 + i) * 65 + c] = acc[i];
  float s2 = 0.f;
  if (t < 64) {
    for (int s = 0; s < 64; s++) s2 += wk[s * 64 + t];
  }
  __syncthreads();
  if (t < 64) cw[g * 64 + t] = s2;
  // Permute: thread t (as a kB thread) needs M[row+i][r*16+col], i=0..3
  int lane = t & 63, wv = t >> 6;
  int row = wv * 16 + ((lane >> 4) << 2);
  int col = lane & 15;
  #pragma unroll
  for (int r = 0; r < 4; r++) {
    float4 mv;
    mv.x = Ml[(row + 0) * 65 + r * 16 + col];
    mv.y = Ml[(row + 1) * 65 + r * 16 + col];
    mv.z = Ml[(row + 2) * 65 + r * 16 + col];
    mv.w = Ml[(row + 3) * 65 + r * 16 + col];
    Mp[(size_t)(g * 4 + r) * 256 + t] = mv;
  }
}

// ---- Kernel B: per (bg, n-chunk): y[n] = w.x (fp32), SumK partial (fp32),
// ----           SumK2 partial via bf16 Gram MFMA + coalesced <Mp, .> --------
__global__ __launch_bounds__(256, 4) void kB(const float* __restrict__ x,
                                             const float* __restrict__ w_all,
                                             const float* __restrict__ cw,
                                             const float4* __restrict__ Mp,
                                             float* __restrict__ y_all,
                                             float* __restrict__ sums_part) {
  int bg = blockIdx.y; int b = bg >> 5; int g = bg & 31;
  int n0 = blockIdx.x * 256;
  int t = threadIdx.x;
  int lane = t & 63;
  int wv = t >> 6;

  __shared__ unsigned short xt[64 * NSTR];   // bf16 tile [c][n], 33792 B
  __shared__ float ypart[4 * 256];
  __shared__ float red[8];

  // Coefficients first (oldest in vmcnt queue -> ready first).
  const float* wp = w_all + bg * 64 + wv * 16;
  const float* cwp = cw + g * 64 + wv * 16;
  float4 wq[4], cq[4];
  #pragma unroll
  for (int j = 0; j < 4; j++) { wq[j] = *(const float4*)(wp + j * 4); }
  #pragma unroll
  for (int j = 0; j < 4; j++) { cq[j] = *(const float4*)(cwp + j * 4); }

  // Batch: all 16 x row-loads in flight (wave wv owns rows c = wv*16..+15).
  const float* xb = x + ((size_t)(b * 2048 + g * 64 + wv * 16)) * NN + n0 + lane * 4;
  float4 v[16];
  #pragma unroll
  for (int k = 0; k < 16; k++) v[k] = *(const float4*)(xb + (size_t)k * NN);

  float y0 = 0, y1 = 0, y2 = 0, y3 = 0, zt = 0;
  unsigned short* xrow = &xt[(wv * 16) * NSTR + lane * 4];
  #pragma unroll
  for (int k = 0; k < 16; k++) {
    float wc = ((const float*)&wq[0])[k];
    float cc = ((const float*)&cq[0])[k];
    float4 vx = v[k];
    y0 += wc * vx.x; y1 += wc * vx.y; y2 += wc * vx.z; y3 += wc * vx.w;
    zt += cc * (vx.x + vx.y + vx.z + vx.w);
    // bf16 pack: +0x8000 round-half, truncate (0.5 ulp, fine for variance)
    unsigned a0 = __builtin_bit_cast(unsigned, vx.x) + 0x8000u;
    unsigned a1 = __builtin_bit_cast(unsigned, vx.y) + 0x8000u;
    unsigned a2 = __builtin_bit_cast(unsigned, vx.z) + 0x8000u;
    unsigned a3 = __builtin_bit_cast(unsigned, vx.w) + 0x8000u;
    uint2 pk;
    pk.x = (a0 >> 16) | (a1 & 0xffff0000u);
    pk.y = (a2 >> 16) | (a3 & 0xffff0000u);
    *(uint2*)(xrow + k * NSTR) = pk;
  }
  {
    float4 yp; yp.x = y0; yp.y = y1; yp.z = y2; yp.w = y3;
    *(float4*)&ypart[wv * 256 + lane * 4] = yp;
  }
  __syncthreads();
  // y final (fp32): thread t -> column t
  y_all[(size_t)bg * NN + n0 + t] =
      ypart[t] + ypart[256 + t] + ypart[512 + t] + ypart[768 + t];

  // Gram MFMA: wave wv computes tile-row wv of C = X X^T (4 16x16 tiles).
  int rbase = (lane & 15) * NSTR;
  int koff = (lane >> 4) * 8;
  int abase = (wv * 16 + (lane & 15)) * NSTR + koff;
  f32x4 acc[4];
  #pragma unroll
  for (int r = 0; r < 4; r++) acc[r] = (f32x4){0.f, 0.f, 0.f, 0.f};
  #pragma unroll
  for (int kk = 0; kk < 8; kk++) {
    uint4 au = *(const uint4*)&xt[abase + kk * 32];
    bf16x8 af = __builtin_bit_cast(bf16x8, au);
    #pragma unroll
    for (int r = 0; r < 4; r++) {
      uint4 bu = *(const uint4*)&xt[r * 16 * NSTR + rbase + kk * 32 + koff];
      bf16x8 bf = __builtin_bit_cast(bf16x8, bu);
      acc[r] = __builtin_amdgcn_mfma_f32_16x16x32_bf16(af, bf, acc[r], 0, 0, 0);
    }
  }
  // <M, Gram> via pre-permuted Mp: 4 coalesced float4 loads.
  float s2acc = 0.f;
  {
    const float4* mp = Mp + (size_t)g * 1024 + t;
    #pragma unroll
    for (int r = 0; r < 4; r++) {
      float4 mv = mp[r * 256];
      s2acc += acc[r][0] * mv.x + acc[r][1] * mv.y +
               acc[r][2] * mv.z + acc[r][3] * mv.w;
    }
  }
  for (int off = 32; off; off >>= 1) {
    zt += __shfl_xor(zt, off);
    s2acc += __shfl_xor(s2acc, off);
  }
  if (lane == 0) { red[wv] = zt; red[4 + wv] = s2acc; }
  __syncthreads();
  if (t == 0) {
    float* sp = sums_part + (size_t)(blockIdx.x * 256 + bg) * 2;
    sp[0] = red[0] + red[1] + red[2] + red[3];
    sp[1] = red[4] + red[5] + red[6] + red[7];
  }
}

// ---- Kernel C: per bg: rs from summed partials, softmax over 4096 logits ---
__global__ __launch_bounds__(256) void kC(const float* __restrict__ y_all,
                                          const float* __restrict__ sums_part,
                                          float* __restrict__ attn) {
  int bg = blockIdx.x; int t = threadIdx.x;
  float s1 = 0.f, s2 = 0.f;
  for (int i = 0; i < NCHUNK; i++) {
    const float* sp = sums_part + (size_t)(i * 256 + bg) * 2;
    s1 += sp[0]; s2 += sp[1];
  }
  float mu = s1 * (1.f / 262144.f);
  float var = s2 * (1.f / 262144.f) - mu * mu;
  float rs = rsqrtf(var + EPS);
  const float* y = y_all + (size_t)bg * NN;
  float l[16];
  float m = -1e30f;
  #pragma unroll
  for (int i = 0; i < 16; i++) {
    l[i] = rs * y[t + 256 * i];
    m = fmaxf(m, l[i]);
  }
  __shared__ float red[8];
  for (int off = 32; off; off >>= 1) m = fmaxf(m, __shfl_xor(m, off));
  int wv = t >> 6, lane = t & 63;
  if (lane == 0) red[wv] = m;
  __syncthreads();
  m = fmaxf(fmaxf(red[0], red[1]), fmaxf(red[2], red[3]));
  float sum = 0.f;
  #pragma unroll
  for (int i = 0; i < 16; i++) { l[i] = __expf(l[i] - m); sum += l[i]; }
  for (int off = 32; off; off >>= 1) sum += __shfl_xor(sum, off);
  if (lane == 0) red[4 + wv] = sum;
  __syncthreads();
  float inv = 1.f / (red[4] + red[5] + red[6] + red[7]);
  float* ao = attn + (size_t)bg * NN;
  #pragma unroll
  for (int i = 0; i < 16; i++) ao[t + 256 * i] = l[i] * inv;
}

// ---- Kernel D: outp[j][bg][c] = sum_{n in chunk j} attn[n]*x[c,n] ----------
__global__ __launch_bounds__(256, 4) void kD(const float* __restrict__ x,
                                             const float* __restrict__ attn,
                                             float* __restrict__ outp) {
  // Reverse order: anti-LRU re-read of x against the 256 MiB L3.
  int bg = 255 - blockIdx.y; int b = bg >> 5; int g = bg & 31;
  int n0 = (NCHUNK - 1 - blockIdx.x) * 256;
  int t = threadIdx.x; int lane = t & 63; int wv = t >> 6;
  // attn first (oldest in queue), then all 16 x loads in flight.
  float4 a = *(const float4*)(attn + (size_t)bg * NN + n0 + lane * 4);
  const float* xb = x + ((size_t)(b * 2048 + g * 64 + wv * 16)) * NN + n0 + lane * 4;
  float4 v[16];
  #pragma unroll
  for (int k = 0; k < 16; k++) v[k] = *(const float4*)(xb + (size_t)k * NN);
  float p[16];
  #pragma unroll
  for (int k = 0; k < 16; k++)
    p[k] = a.x * v[k].x + a.y * v[k].y + a.z * v[k].z + a.w * v[k].w;
  #pragma unroll
  for (int k = 0; k < 16; k++) {
    float r = p[k];
    for (int off = 32; off; off >>= 1) r += __shfl_xor(r, off);
    if (lane == 0)
      outp[(size_t)blockIdx.x * 16384 + bg * 64 + wv * 16 + k] = r;
  }
}

// ---- Kernel E: out[bg][s] = sum_c (sum_j outp[j][bg][c]) * Wv[g][s][c] -----
__global__ __launch_bounds__(64) void kE(const float* __restrict__ outp,
                                         const float* __restrict__ Wv,
                                         float* __restrict__ out) {
  int bg = blockIdx.x; int g = bg & 31;
  int t = threadIdx.x;
  __shared__ float oc[64];
  __shared__ float wvs[64 * 65];
  float s = 0.f;
  #pragma unroll
  for (int j = 0; j < NCHUNK; j++) s += outp[j * 16384 + bg * 64 + t];
  oc[t] = s;
  const float* wg = Wv + (size_t)g * 4096;
  for (int i = 0; i < 64; i++) wvs[i * 65 + t] = wg[i * 64 + t];
  __syncthreads();
  float acc = 0.f;
  for (int c = 0; c < 64; c++) acc += wvs[t * 65 + c] * oc[c];
  out[bg * 64 + t] = acc;
}

extern "C" void kernel_launch(void* const* d_in, const int* in_sizes, int n_in,
                              void* d_out, int out_size, void* d_ws, size_t ws_size,
                              hipStream_t stream) {
  const float* x    = (const float*)d_in[0];
  const float* sent = (const float*)d_in[1];
  const float* Wq   = (const float*)d_in[2];
  const float* Wk   = (const float*)d_in[3];
  const float* Wv   = (const float*)d_in[4];
  const float* g1   = (const float*)d_in[5];
  const float* b1   = (const float*)d_in[6];
  const float* g2   = (const float*)d_in[7];
  // d_in[8] = beta2: drops out of softmax (shift-invariance) — unused.
  float* out = (float*)d_out;

  char* ws = (char*)d_ws;
  float*  w_all = (float*)(ws);                 // 256*64*4        = 64 KB
  float*  cw    = (float*)(ws + 65536);         // 32*64*4         = 8 KB
  float4* Mp    = (float4*)(ws + 73728);        // 32*4*256*16     = 512 KB
  float*  sumsp = (float*)(ws + 598016);        // 16*256*2*4      = 32 KB
  float*  outp  = (float*)(ws + 630784);        // 16*256*64*4     = 1 MB
  float*  y_all = (float*)(ws + 1679360);       // 256*4096*4      = 4 MB
  float*  attn  = (float*)(ws + 5873664);       // 4 MB

  kA<<<256, 64, 0, stream>>>(sent, Wq, Wk, g1, b1, g2, w_all);
  kM<<<32, 256, 0, stream>>>(Wk, Mp, cw);
  kB<<<dim3(NCHUNK, 256), 256, 0, stream>>>(x, w_all, cw, Mp, y_all, sumsp);
  kC<<<256, 256, 0, stream>>>(y_all, sumsp, attn);
  kD<<<dim3(NCHUNK, 256), 256, 0, stream>>>(x, attn, outp);
  kE<<<256, 64, 0, stream>>>(outp, Wv, out);
}